// Round 1
// baseline (648.185 us; speedup 1.0000x reference)
//
#include <hip/hip_runtime.h>
#include <hip/hip_bf16.h>

#define NN 64
#define CC 512
#define MM 1600
#define KK 64
#define EPSF 1e-12f

__device__ inline unsigned short f2bf(float f) {
    unsigned int u = __float_as_uint(f);
    unsigned int r = u + 0x7fffu + ((u >> 16) & 1u);   // round-to-nearest-even
    return (unsigned short)(r >> 16);
}

// ---------------------------------------------------------------------------
// K1: per (n, 64-pixel tile): pixel L2 norms + logits GEMM + softmax over K
//     -> a (bf16), rnorm, asum (atomic)
// block = 128 threads: mq = t&15 (4 pixels each), kq = t>>4 (8 k's each)
// ---------------------------------------------------------------------------
__global__ __launch_bounds__(128) void assign_kernel(
    const float* __restrict__ x, const float* __restrict__ w,
    const float* __restrict__ bias, unsigned short* __restrict__ abuf,
    float* __restrict__ rnorm, float* __restrict__ asum)
{
    __shared__ __attribute__((aligned(16))) float ws_l[64][68]; // w chunk, [c][k]
    __shared__ float red[64][8];
    __shared__ float rmax_l[64];
    __shared__ float rinv_l[64];
    __shared__ float rn_l[64];
    __shared__ float asl[64][16];

    const int t  = threadIdx.x;
    const int n  = blockIdx.y;
    const int m0 = blockIdx.x * 64;
    const int mq = t & 15;   // pixel-quad
    const int kq = t >> 4;   // 0..7 (also used as c-slice in norm phase)

    // ---- phase 1: per-pixel sum of squares over C (x read from HBM once) ----
    {
        float s0 = 0.f, s1 = 0.f, s2 = 0.f, s3 = 0.f;
        const float* xp = x + (n * CC) * MM + m0 + mq * 4;
        #pragma unroll 8
        for (int c = kq * 64; c < kq * 64 + 64; ++c) {
            float4 v = *(const float4*)(xp + (long)c * MM);
            s0 += v.x * v.x; s1 += v.y * v.y; s2 += v.z * v.z; s3 += v.w * v.w;
        }
        red[mq * 4 + 0][kq] = s0; red[mq * 4 + 1][kq] = s1;
        red[mq * 4 + 2][kq] = s2; red[mq * 4 + 3][kq] = s3;
    }
    __syncthreads();
    if (t < 64) {
        float s = 0.f;
        #pragma unroll
        for (int p = 0; p < 8; ++p) s += red[t][p];
        float rn = 1.0f / fmaxf(sqrtf(s), EPSF);
        rn_l[t] = rn;
        rnorm[n * MM + m0 + t] = rn;
    }
    __syncthreads();

    float rn0 = rn_l[mq * 4 + 0], rn1 = rn_l[mq * 4 + 1];
    float rn2 = rn_l[mq * 4 + 2], rn3 = rn_l[mq * 4 + 3];

    // ---- phase 2: logits GEMM  acc[k][m] = sum_c w[k][c] * x_raw[c][m] ----
    float acc[8][4];
    #pragma unroll
    for (int i = 0; i < 8; ++i)
        #pragma unroll
        for (int j = 0; j < 4; ++j) acc[i][j] = 0.f;

    for (int cc = 0; cc < 8; ++cc) {
        __syncthreads();
        #pragma unroll
        for (int i = 0; i < 32; ++i) {             // stage w chunk transposed
            int idx = i * 128 + t;
            int ci = idx & 63, k = idx >> 6;
            ws_l[ci][k] = w[k * CC + cc * 64 + ci];
        }
        __syncthreads();
        const float* xp = x + (n * CC + cc * 64) * MM + m0 + mq * 4;
        #pragma unroll 4
        for (int ci = 0; ci < 64; ++ci) {
            float4 xv = *(const float4*)(xp + (long)ci * MM);
            float wreg[8];
            *(float4*)&wreg[0] = *(float4*)&ws_l[ci][kq * 8];
            *(float4*)&wreg[4] = *(float4*)&ws_l[ci][kq * 8 + 4];
            #pragma unroll
            for (int i = 0; i < 8; ++i) {
                acc[i][0] += wreg[i] * xv.x;
                acc[i][1] += wreg[i] * xv.y;
                acc[i][2] += wreg[i] * xv.z;
                acc[i][3] += wreg[i] * xv.w;
            }
        }
    }

    // ---- phase 3: logits = acc*rn + b, softmax over K (cross-thread via LDS)
    float bb[8];
    #pragma unroll
    for (int i = 0; i < 8; ++i) bb[i] = bias[kq * 8 + i];

    float l[8][4];
    #pragma unroll
    for (int i = 0; i < 8; ++i) {
        l[i][0] = acc[i][0] * rn0 + bb[i];
        l[i][1] = acc[i][1] * rn1 + bb[i];
        l[i][2] = acc[i][2] * rn2 + bb[i];
        l[i][3] = acc[i][3] * rn3 + bb[i];
    }
    __syncthreads();   // red reuse safe (norm-phase readers long done)
    #pragma unroll
    for (int j = 0; j < 4; ++j) {
        float mx = l[0][j];
        #pragma unroll
        for (int i = 1; i < 8; ++i) mx = fmaxf(mx, l[i][j]);
        red[mq * 4 + j][kq] = mx;
    }
    __syncthreads();
    if (t < 64) {
        float mx = red[t][0];
        #pragma unroll
        for (int p = 1; p < 8; ++p) mx = fmaxf(mx, red[t][p]);
        rmax_l[t] = mx;
    }
    __syncthreads();
    #pragma unroll
    for (int j = 0; j < 4; ++j) {
        float mx = rmax_l[mq * 4 + j];
        float s = 0.f;
        #pragma unroll
        for (int i = 0; i < 8; ++i) { l[i][j] = expf(l[i][j] - mx); s += l[i][j]; }
        red[mq * 4 + j][kq] = s;
    }
    __syncthreads();
    if (t < 64) {
        float s = 0.f;
        #pragma unroll
        for (int p = 0; p < 8; ++p) s += red[t][p];
        rinv_l[t] = 1.0f / s;
    }
    __syncthreads();

    float ri0 = rinv_l[mq * 4 + 0], ri1 = rinv_l[mq * 4 + 1];
    float ri2 = rinv_l[mq * 4 + 2], ri3 = rinv_l[mq * 4 + 3];
    #pragma unroll
    for (int i = 0; i < 8; ++i) {
        float a0 = l[i][0] * ri0, a1 = l[i][1] * ri1;
        float a2 = l[i][2] * ri2, a3 = l[i][3] * ri3;
        ushort4 u;
        u.x = f2bf(a0); u.y = f2bf(a1); u.z = f2bf(a2); u.w = f2bf(a3);
        *(ushort4*)(abuf + (long)(n * KK + kq * 8 + i) * MM + m0 + mq * 4) = u;
        asl[kq * 8 + i][mq] = a0 + a1 + a2 + a3;
    }
    __syncthreads();
    if (t < 64) {
        float s = 0.f;
        #pragma unroll
        for (int q = 0; q < 16; ++q) s += asl[t][q];
        atomicAdd(&asum[n * KK + t], s);
    }
}

// ---------------------------------------------------------------------------
// K2: agg[n,k,c] += sum_m a[n,k,m] * x[n,c,m] * rnorm[n,m]
// block = 256: cq = t&31 (4 c's), kq = t>>5 (8 k's); (n, c-tile, m-split) grid
// ---------------------------------------------------------------------------
__global__ __launch_bounds__(256) void agg_kernel(
    const float* __restrict__ x, const unsigned short* __restrict__ abuf,
    const float* __restrict__ rnorm, float* __restrict__ agg)
{
    __shared__ __attribute__((aligned(16))) float xt[32][132];  // [m][c] tile
    __shared__ __attribute__((aligned(16))) float as_l[32][68]; // [m][k] tile

    const int t  = threadIdx.x;
    const int n  = blockIdx.y;
    const int ct = blockIdx.x >> 2;  // c-tile 0..3
    const int ms = blockIdx.x & 3;   // m-split 0..3
    const int c0 = ct * 128;
    const int cq = t & 31;
    const int kq = t >> 5;

    float acc[8][4];
    #pragma unroll
    for (int i = 0; i < 8; ++i)
        #pragma unroll
        for (int j = 0; j < 4; ++j) acc[i][j] = 0.f;

    for (int mc = ms; mc < 50; mc += 4) {
        const int m0 = mc * 32;
        __syncthreads();
        #pragma unroll
        for (int i = 0; i < 16; ++i) {           // stage x (transposed, *rnorm)
            int idx = i * 256 + t;
            int mm = idx & 31, ci = idx >> 5;
            float v = x[(long)(n * CC + c0 + ci) * MM + m0 + mm]
                      * rnorm[n * MM + m0 + mm];
            xt[mm][ci] = v;
        }
        #pragma unroll
        for (int i = 0; i < 8; ++i) {            // stage a (bf16 -> f32)
            int idx = i * 256 + t;
            int mm = idx & 31, k = idx >> 5;
            unsigned int ub = abuf[(long)(n * KK + k) * MM + m0 + mm];
            as_l[mm][k] = __uint_as_float(ub << 16);
        }
        __syncthreads();
        #pragma unroll 4
        for (int mm = 0; mm < 32; ++mm) {
            float a8[8];
            *(float4*)&a8[0] = *(float4*)&as_l[mm][kq * 8];
            *(float4*)&a8[4] = *(float4*)&as_l[mm][kq * 8 + 4];
            float4 xv = *(float4*)&xt[mm][cq * 4];
            #pragma unroll
            for (int i = 0; i < 8; ++i) {
                acc[i][0] += a8[i] * xv.x;
                acc[i][1] += a8[i] * xv.y;
                acc[i][2] += a8[i] * xv.z;
                acc[i][3] += a8[i] * xv.w;
            }
        }
    }
    #pragma unroll
    for (int i = 0; i < 8; ++i) {
        float* dst = agg + (long)(n * KK + kq * 8 + i) * CC + c0 + cq * 4;
        atomicAdd(dst + 0, acc[i][0]);
        atomicAdd(dst + 1, acc[i][1]);
        atomicAdd(dst + 2, acc[i][2]);
        atomicAdd(dst + 3, acc[i][3]);
    }
}

// ---------------------------------------------------------------------------
// K3a: vlad = agg - asum*cent, intra-normalize over C, accumulate global sumsq
// ---------------------------------------------------------------------------
__global__ __launch_bounds__(256) void vlad_kernel(
    const float* __restrict__ agg, const float* __restrict__ asum,
    const float* __restrict__ cent, float* __restrict__ out,
    float* __restrict__ gns)
{
    __shared__ float wsum[4];
    __shared__ float sinv;
    const int nk = blockIdx.x;          // n*64 + k
    const int n = nk >> 6, k = nk & 63;
    const int t = threadIdx.x;

    float s = asum[nk];
    float2 av = *(const float2*)(agg + (long)nk * CC + 2 * t);
    float2 cv = *(const float2*)(cent + (long)k * CC + 2 * t);
    float v0 = av.x - s * cv.x;
    float v1 = av.y - s * cv.y;
    float ss = v0 * v0 + v1 * v1;
    #pragma unroll
    for (int o = 32; o > 0; o >>= 1) ss += __shfl_down(ss, o);
    int lane = t & 63, wid = t >> 6;
    if (lane == 0) wsum[wid] = ss;
    __syncthreads();
    if (t == 0) {
        float tot = wsum[0] + wsum[1] + wsum[2] + wsum[3];
        float inv = 1.0f / fmaxf(sqrtf(tot), EPSF);
        sinv = inv;
        atomicAdd(&gns[n], tot * inv * inv);
    }
    __syncthreads();
    float inv = sinv;
    float2 o2; o2.x = v0 * inv; o2.y = v1 * inv;
    *(float2*)(out + (long)nk * CC + 2 * t) = o2;
}

// ---------------------------------------------------------------------------
// K3b: global L2 scale per n
// ---------------------------------------------------------------------------
__global__ __launch_bounds__(256) void gscale_kernel(
    float* __restrict__ out, const float* __restrict__ gns)
{
    int idx = blockIdx.x * 256 + threadIdx.x;   // float4 index; 524288 total
    int n = idx >> 13;                          // 8192 float4 per n
    float inv = 1.0f / fmaxf(sqrtf(gns[n]), EPSF);
    float4 v = *(float4*)(out + (long)idx * 4);
    v.x *= inv; v.y *= inv; v.z *= inv; v.w *= inv;
    *(float4*)(out + (long)idx * 4) = v;
}

extern "C" void kernel_launch(void* const* d_in, const int* in_sizes, int n_in,
                              void* d_out, int out_size, void* d_ws, size_t ws_size,
                              hipStream_t stream)
{
    const float* x    = (const float*)d_in[0];
    const float* w    = (const float*)d_in[1];
    const float* bias = (const float*)d_in[2];
    const float* cent = (const float*)d_in[3];
    float* out = (float*)d_out;

    char* ws = (char*)d_ws;
    const size_t abuf_b  = (size_t)NN * KK * MM * 2;      // 13,107,200
    const size_t rnorm_b = (size_t)NN * MM * 4;           //    409,600
    const size_t agg_b   = (size_t)NN * KK * CC * 4;      //  8,388,608
    const size_t asum_b  = (size_t)NN * KK * 4;           //     16,384
    const size_t gns_b   = (size_t)NN * 4;                //        256

    unsigned short* abuf = (unsigned short*)ws;
    float* rnorm = (float*)(ws + abuf_b);
    float* agg   = (float*)(ws + abuf_b + rnorm_b);
    float* asum  = (float*)(ws + abuf_b + rnorm_b + agg_b);
    float* gns   = (float*)(ws + abuf_b + rnorm_b + agg_b + asum_b);

    // zero the accumulated buffers (agg, asum, gns are contiguous)
    hipMemsetAsync(agg, 0, agg_b + asum_b + gns_b, stream);

    assign_kernel<<<dim3(25, 64), 128, 0, stream>>>(x, w, bias, abuf, rnorm, asum);
    agg_kernel  <<<dim3(16, 64), 256, 0, stream>>>(x, abuf, rnorm, agg);
    vlad_kernel <<<NN * KK, 256, 0, stream>>>(agg, asum, cent, out, gns);
    gscale_kernel<<<(out_size / 4 + 255) / 256, 256, 0, stream>>>(out, gns);
}

// Round 2
// 229.369 us; speedup vs baseline: 2.8260x; 2.8260x over previous
//
#include <hip/hip_runtime.h>
#include <hip/hip_bf16.h>

#define NN 64
#define CC 512
#define MM 1600
#define KK 64
#define EPSF 1e-12f

typedef __attribute__((ext_vector_type(4))) float f32x4;
typedef __attribute__((ext_vector_type(8))) short bf16x8;

__device__ inline unsigned short f2bf(float f) {
    unsigned int u = __float_as_uint(f);
    unsigned int r = u + 0x7fffu + ((u >> 16) & 1u);   // RNE
    return (unsigned short)(r >> 16);
}

// ---------------------------------------------------------------------------
// prep: read x f32 once; write xb bf16 [n][c][m], xbt bf16 [n][m][c], rnorm.
// block 256, grid (25 m-tiles, 64 n). LDS transpose per 64c x 64m chunk.
// ---------------------------------------------------------------------------
__global__ __launch_bounds__(256) void prep_kernel(
    const float* __restrict__ x, unsigned short* __restrict__ xb,
    unsigned short* __restrict__ xbt, float* __restrict__ rn)
{
    __shared__ __attribute__((aligned(16))) unsigned short lds_t[64][72];
    const int t  = threadIdx.x;
    const int n  = blockIdx.y;
    const int m0 = blockIdx.x * 64;
    const int m4 = t & 15;    // float4 column within m-tile
    const int cl = t >> 4;    // 0..15

    float ss[4] = {0.f, 0.f, 0.f, 0.f};

    for (int cc = 0; cc < 8; ++cc) {
        #pragma unroll
        for (int p = 0; p < 4; ++p) {
            const int c = cc * 64 + p * 16 + cl;
            const float4 v = *(const float4*)(x + ((size_t)(n * CC + c)) * MM + m0 + m4 * 4);
            ss[0] += v.x * v.x; ss[1] += v.y * v.y; ss[2] += v.z * v.z; ss[3] += v.w * v.w;
            ushort4 b;
            b.x = f2bf(v.x); b.y = f2bf(v.y); b.z = f2bf(v.z); b.w = f2bf(v.w);
            *(ushort4*)(xb + ((size_t)(n * CC + c)) * MM + m0 + m4 * 4) = b;
            const int c_loc = p * 16 + cl;
            lds_t[m4 * 4 + 0][c_loc] = b.x;
            lds_t[m4 * 4 + 1][c_loc] = b.y;
            lds_t[m4 * 4 + 2][c_loc] = b.z;
            lds_t[m4 * 4 + 3][c_loc] = b.w;
        }
        __syncthreads();
        {
            const int m_l = t >> 2, q = t & 3;
            uint4 w0 = *(uint4*)&lds_t[m_l][q * 16];
            uint4 w1 = *(uint4*)&lds_t[m_l][q * 16 + 8];
            unsigned short* dst = xbt + ((size_t)(n * MM + m0 + m_l)) * CC + cc * 64 + q * 16;
            *(uint4*)dst = w0;
            *(uint4*)(dst + 8) = w1;
        }
        __syncthreads();
    }
    // reduce sum-of-squares over the 16 cl-groups -> rnorm
    float* red = (float*)&lds_t[0][0];   // [16][64] f32 overlay (4 KB < 9.2 KB)
    #pragma unroll
    for (int j = 0; j < 4; ++j) red[cl * 64 + m4 * 4 + j] = ss[j];
    __syncthreads();
    if (t < 64) {
        float s = 0.f;
        #pragma unroll
        for (int i = 0; i < 16; ++i) s += red[i * 64 + t];
        rn[n * MM + m0 + t] = 1.0f / fmaxf(sqrtf(s), EPSF);
    }
}

// ---------------------------------------------------------------------------
// w -> bf16
// ---------------------------------------------------------------------------
__global__ __launch_bounds__(256) void wconv_kernel(
    const float* __restrict__ w, unsigned short* __restrict__ wb)
{
    const int i = (blockIdx.x * 256 + threadIdx.x) * 8;
    float4 a = *(const float4*)(w + i);
    float4 b = *(const float4*)(w + i + 4);
    ushort4 u0, u1;
    u0.x = f2bf(a.x); u0.y = f2bf(a.y); u0.z = f2bf(a.z); u0.w = f2bf(a.w);
    u1.x = f2bf(b.x); u1.y = f2bf(b.y); u1.z = f2bf(b.z); u1.w = f2bf(b.w);
    *(ushort4*)(wb + i) = u0;
    *(ushort4*)(wb + i + 4) = u1;
}

// ---------------------------------------------------------------------------
// logits: MFMA D[k=64][m16 per wave] over C=512; softmax over k; write
// a' = a*rnorm bf16 [n][k][m]; atomic asum. grid (25, 64), block 256.
// ---------------------------------------------------------------------------
__global__ __launch_bounds__(256) void logits_kernel(
    const unsigned short* __restrict__ xbt, const unsigned short* __restrict__ wb,
    const float* __restrict__ bias, const float* __restrict__ rn,
    unsigned short* __restrict__ ap, float* __restrict__ asum)
{
    __shared__ float als[64][68];   // a (unscaled), [k][m-tile]
    __shared__ float rn_l[64];
    const int t    = threadIdx.x;
    const int n    = blockIdx.y;
    const int m0   = blockIdx.x * 64;
    const int wv   = t >> 6;
    const int lane = t & 63;
    const int g    = lane >> 4;   // 0..3
    const int lr   = lane & 15;
    const int m_lane = m0 + wv * 16 + lr;

    f32x4 acc[4];
    #pragma unroll
    for (int kt = 0; kt < 4; ++kt) acc[kt] = (f32x4){0.f, 0.f, 0.f, 0.f};

    const unsigned short* xrow = xbt + ((size_t)(n * MM + m_lane)) * CC + g * 8;
    const unsigned short* wrow = wb + g * 8;

    #pragma unroll 4
    for (int cs = 0; cs < CC; cs += 32) {
        bf16x8 bfrag = *(const bf16x8*)(xrow + cs);   // B: col=m (lr), k=c
        #pragma unroll
        for (int kt = 0; kt < 4; ++kt) {
            bf16x8 afrag = *(const bf16x8*)(wrow + (kt * 16 + lr) * CC + cs); // A: row=k
            acc[kt] = __builtin_amdgcn_mfma_f32_16x16x32_bf16(afrag, bfrag, acc[kt], 0, 0, 0);
        }
    }

    const float rnm = rn[n * MM + m_lane];
    if (g == 0) rn_l[wv * 16 + lr] = rnm;

    // lane holds k = kt*16 + g*4 + r for its m; softmax over k
    float l[16];
    #pragma unroll
    for (int kt = 0; kt < 4; ++kt) {
        float4 bb = *(const float4*)(bias + kt * 16 + g * 4);
        l[kt * 4 + 0] = acc[kt][0] * rnm + bb.x;
        l[kt * 4 + 1] = acc[kt][1] * rnm + bb.y;
        l[kt * 4 + 2] = acc[kt][2] * rnm + bb.z;
        l[kt * 4 + 3] = acc[kt][3] * rnm + bb.w;
    }
    float mx = l[0];
    #pragma unroll
    for (int i = 1; i < 16; ++i) mx = fmaxf(mx, l[i]);
    mx = fmaxf(mx, __shfl_xor(mx, 16));
    mx = fmaxf(mx, __shfl_xor(mx, 32));
    float s = 0.f;
    #pragma unroll
    for (int i = 0; i < 16; ++i) { l[i] = __expf(l[i] - mx); s += l[i]; }
    s += __shfl_xor(s, 16);
    s += __shfl_xor(s, 32);
    const float inv = 1.0f / s;
    #pragma unroll
    for (int kt = 0; kt < 4; ++kt)
        #pragma unroll
        for (int r = 0; r < 4; ++r)
            als[kt * 16 + g * 4 + r][wv * 16 + lr] = l[kt * 4 + r] * inv;
    __syncthreads();

    // write a' = a*rnorm (bf16) row-wise + asum
    {
        const int k = t >> 2, q = t & 3;
        float spart = 0.f;
        unsigned short ub[16];
        #pragma unroll
        for (int i = 0; i < 16; ++i) {
            float a = als[k][q * 16 + i];
            spart += a;
            ub[i] = f2bf(a * rn_l[q * 16 + i]);
        }
        unsigned short* dst = ap + ((size_t)(n * KK + k)) * MM + m0 + q * 16;
        *(uint4*)dst = *(uint4*)&ub[0];
        *(uint4*)(dst + 8) = *(uint4*)&ub[8];
        spart += __shfl_xor(spart, 1);
        spart += __shfl_xor(spart, 2);
        if (q == 0) atomicAdd(asum + n * KK + k, spart);
    }
}

// ---------------------------------------------------------------------------
// agg: D[k=64][c32 per wave] = sum_m a'[k][m] * xb[c][m]. a' staged in LDS
// (pad 72 -> 2-way=free), xb fragments direct from global (L3).
// grid (8 = 4 c-tiles x 2 m-splits, 64 n), block 256. atomicAdd into agg.
// ---------------------------------------------------------------------------
__global__ __launch_bounds__(256) void aggm_kernel(
    const unsigned short* __restrict__ xb, const unsigned short* __restrict__ ap,
    float* __restrict__ agg)
{
    __shared__ __attribute__((aligned(16))) unsigned short als2[64][72];
    const int t      = threadIdx.x;
    const int n      = blockIdx.y;
    const int ct     = blockIdx.x & 3;
    const int msplit = blockIdx.x >> 2;
    const int wv     = t >> 6;
    const int lane   = t & 63;
    const int g      = lane >> 4;
    const int lr     = lane & 15;
    const int c_w    = ct * 128 + wv * 32;

    f32x4 acc[4][2];
    #pragma unroll
    for (int kt = 0; kt < 4; ++kt)
        #pragma unroll
        for (int cb = 0; cb < 2; ++cb) acc[kt][cb] = (f32x4){0.f, 0.f, 0.f, 0.f};

    const int ks = t >> 2, qs = t & 3;   // staging coords

    for (int mcb = msplit; mcb < 25; mcb += 2) {
        const int mc = mcb * 64;
        __syncthreads();
        {
            const unsigned short* src = ap + ((size_t)(n * KK + ks)) * MM + mc + qs * 16;
            uint4 w0 = *(const uint4*)src;
            uint4 w1 = *(const uint4*)(src + 8);
            *(uint4*)&als2[ks][qs * 16] = w0;
            *(uint4*)&als2[ks][qs * 16 + 8] = w1;
        }
        __syncthreads();
        #pragma unroll
        for (int msi = 0; msi < 2; ++msi) {
            const int ms = msi * 32;
            bf16x8 af[4];
            #pragma unroll
            for (int kt = 0; kt < 4; ++kt)
                af[kt] = *(const bf16x8*)&als2[kt * 16 + lr][ms + g * 8];   // A: row=k, 8 m
            #pragma unroll
            for (int cb = 0; cb < 2; ++cb) {
                bf16x8 bf = *(const bf16x8*)(xb +
                    ((size_t)(n * CC + c_w + cb * 16 + lr)) * MM + mc + ms + g * 8); // B^T row
                #pragma unroll
                for (int kt = 0; kt < 4; ++kt)
                    acc[kt][cb] = __builtin_amdgcn_mfma_f32_16x16x32_bf16(af[kt], bf, acc[kt][cb], 0, 0, 0);
            }
        }
    }
    #pragma unroll
    for (int kt = 0; kt < 4; ++kt)
        #pragma unroll
        for (int cb = 0; cb < 2; ++cb)
            #pragma unroll
            for (int r = 0; r < 4; ++r) {
                const int k = kt * 16 + g * 4 + r;
                const int c = c_w + cb * 16 + lr;
                atomicAdd(agg + ((size_t)(n * KK + k)) * CC + c, acc[kt][cb][r]);
            }
}

// ---------------------------------------------------------------------------
// vlad = agg - asum*cent, intra-normalize over C, accumulate global sumsq
// ---------------------------------------------------------------------------
__global__ __launch_bounds__(256) void vlad_kernel(
    const float* __restrict__ agg, const float* __restrict__ asum,
    const float* __restrict__ cent, float* __restrict__ out,
    float* __restrict__ gns)
{
    __shared__ float wsum[4];
    __shared__ float sinv;
    const int nk = blockIdx.x;          // n*64 + k
    const int n = nk >> 6, k = nk & 63;
    const int t = threadIdx.x;

    float s = asum[nk];
    float2 av = *(const float2*)(agg + (long)nk * CC + 2 * t);
    float2 cv = *(const float2*)(cent + (long)k * CC + 2 * t);
    float v0 = av.x - s * cv.x;
    float v1 = av.y - s * cv.y;
    float ss = v0 * v0 + v1 * v1;
    #pragma unroll
    for (int o = 32; o > 0; o >>= 1) ss += __shfl_down(ss, o);
    int lane = t & 63, wid = t >> 6;
    if (lane == 0) wsum[wid] = ss;
    __syncthreads();
    if (t == 0) {
        float tot = wsum[0] + wsum[1] + wsum[2] + wsum[3];
        float inv = 1.0f / fmaxf(sqrtf(tot), EPSF);
        sinv = inv;
        atomicAdd(&gns[n], tot * inv * inv);
    }
    __syncthreads();
    float inv = sinv;
    float2 o2; o2.x = v0 * inv; o2.y = v1 * inv;
    *(float2*)(out + (long)nk * CC + 2 * t) = o2;
}

__global__ __launch_bounds__(256) void gscale_kernel(
    float* __restrict__ out, const float* __restrict__ gns)
{
    int idx = blockIdx.x * 256 + threadIdx.x;   // float4 index
    int n = idx >> 13;                          // 8192 float4 per n
    float inv = 1.0f / fmaxf(sqrtf(gns[n]), EPSF);
    float4 v = *(float4*)(out + (long)idx * 4);
    v.x *= inv; v.y *= inv; v.z *= inv; v.w *= inv;
    *(float4*)(out + (long)idx * 4) = v;
}

extern "C" void kernel_launch(void* const* d_in, const int* in_sizes, int n_in,
                              void* d_out, int out_size, void* d_ws, size_t ws_size,
                              hipStream_t stream)
{
    const float* x    = (const float*)d_in[0];
    const float* w    = (const float*)d_in[1];
    const float* bias = (const float*)d_in[2];
    const float* cent = (const float*)d_in[3];
    float* out = (float*)d_out;

    char* ws = (char*)d_ws;
    size_t off = 0;
    unsigned short* xb  = (unsigned short*)(ws + off); off += (size_t)NN * CC * MM * 2;
    unsigned short* xbt = (unsigned short*)(ws + off); off += (size_t)NN * CC * MM * 2;
    unsigned short* ap  = (unsigned short*)(ws + off); off += (size_t)NN * KK * MM * 2;
    unsigned short* wb  = (unsigned short*)(ws + off); off += (size_t)KK * CC * 2;
    float* rn   = (float*)(ws + off); off += (size_t)NN * MM * 4;
    float* agg  = (float*)(ws + off); off += (size_t)NN * KK * CC * 4;
    float* asum = (float*)(ws + off); off += (size_t)NN * KK * 4;
    float* gns  = (float*)(ws + off); off += (size_t)NN * 4;

    // zero agg + asum + gns (contiguous)
    hipMemsetAsync(agg, 0, (size_t)NN * KK * CC * 4 + (size_t)NN * KK * 4 + NN * 4, stream);

    wconv_kernel <<<16, 256, 0, stream>>>(w, wb);
    prep_kernel  <<<dim3(25, 64), 256, 0, stream>>>(x, xb, xbt, rn);
    logits_kernel<<<dim3(25, 64), 256, 0, stream>>>(xbt, wb, bias, rn, ap, asum);
    aggm_kernel  <<<dim3(8, 64), 256, 0, stream>>>(xb, ap, agg);
    vlad_kernel  <<<NN * KK, 256, 0, stream>>>(agg, asum, cent, out, gns);
    gscale_kernel<<<(out_size / 4 + 255) / 256, 256, 0, stream>>>(out, gns);
}

// Round 3
// 139.189 us; speedup vs baseline: 4.6569x; 1.6479x over previous
//
#include <hip/hip_runtime.h>
#include <hip/hip_bf16.h>

#define NN 64
#define CC 512
#define MM 1600
#define KK 64
#define EPSF 1e-12f

typedef __attribute__((ext_vector_type(4))) float f32x4;
typedef __attribute__((ext_vector_type(8))) short bf16x8;

__device__ inline unsigned short f2bf(float f) {
    unsigned int u = __float_as_uint(f);
    unsigned int r = u + 0x7fffu + ((u >> 16) & 1u);   // RNE
    return (unsigned short)(r >> 16);
}

// ---------------------------------------------------------------------------
// w -> bf16
// ---------------------------------------------------------------------------
__global__ __launch_bounds__(256) void wconv_kernel(
    const float* __restrict__ w, unsigned short* __restrict__ wb)
{
    const int i = (blockIdx.x * 256 + threadIdx.x) * 8;
    float4 a = *(const float4*)(w + i);
    float4 b = *(const float4*)(w + i + 4);
    ushort4 u0, u1;
    u0.x = f2bf(a.x); u0.y = f2bf(a.y); u0.z = f2bf(a.z); u0.w = f2bf(a.w);
    u1.x = f2bf(b.x); u1.y = f2bf(b.y); u1.z = f2bf(b.z); u1.w = f2bf(b.w);
    *(ushort4*)(wb + i) = u0;
    *(ushort4*)(wb + i + 4) = u1;
}

// ---------------------------------------------------------------------------
// fused1: per (n, 64-m tile): read x f32 once -> sumsq/rnorm + xb bf16 +
// LDS-transposed chunk -> logits MFMA -> softmax over K -> ap = a*rnorm bf16,
// asum_part (plain stores, no zero-init). grid (25, 64), block 256.
// ---------------------------------------------------------------------------
__global__ __launch_bounds__(256) void fused1_kernel(
    const float* __restrict__ x, const unsigned short* __restrict__ wb,
    const float* __restrict__ bias, unsigned short* __restrict__ xb,
    unsigned short* __restrict__ ap, float* __restrict__ asum_part)
{
    __shared__ __attribute__((aligned(16))) unsigned short lds_t[64][72]; // [m][c_loc]
    __shared__ float als[64][68];   // a (unscaled), [k][m]
    __shared__ float rn_s[64];

    const int t  = threadIdx.x;
    const int n  = blockIdx.y;
    const int mt = blockIdx.x;
    const int m0 = mt * 64;
    const int m4 = t & 15;    // float4 column within m-tile
    const int cl = t >> 4;    // 0..15
    const int wv   = t >> 6;
    const int lane = t & 63;
    const int g    = lane >> 4;   // 0..3
    const int lr   = lane & 15;

    float ss[4] = {0.f, 0.f, 0.f, 0.f};
    f32x4 acc[4];
    #pragma unroll
    for (int kt = 0; kt < 4; ++kt) acc[kt] = (f32x4){0.f, 0.f, 0.f, 0.f};

    for (int cc = 0; cc < 8; ++cc) {
        #pragma unroll
        for (int p = 0; p < 4; ++p) {
            const int c = cc * 64 + p * 16 + cl;
            const float4 v = *(const float4*)(x + ((size_t)(n * CC + c)) * MM + m0 + m4 * 4);
            ss[0] += v.x * v.x; ss[1] += v.y * v.y; ss[2] += v.z * v.z; ss[3] += v.w * v.w;
            ushort4 b;
            b.x = f2bf(v.x); b.y = f2bf(v.y); b.z = f2bf(v.z); b.w = f2bf(v.w);
            *(ushort4*)(xb + ((size_t)(n * CC + c)) * MM + m0 + m4 * 4) = b;
            const int c_loc = p * 16 + cl;
            lds_t[m4 * 4 + 0][c_loc] = b.x;
            lds_t[m4 * 4 + 1][c_loc] = b.y;
            lds_t[m4 * 4 + 2][c_loc] = b.z;
            lds_t[m4 * 4 + 3][c_loc] = b.w;
        }
        __syncthreads();
        #pragma unroll
        for (int cs = 0; cs < 2; ++cs) {
            bf16x8 bfrag = *(const bf16x8*)&lds_t[wv * 16 + lr][cs * 32 + g * 8];
            #pragma unroll
            for (int kt = 0; kt < 4; ++kt) {
                bf16x8 afrag = *(const bf16x8*)(wb + (kt * 16 + lr) * CC + cc * 64 + cs * 32 + g * 8);
                acc[kt] = __builtin_amdgcn_mfma_f32_16x16x32_bf16(afrag, bfrag, acc[kt], 0, 0, 0);
            }
        }
        __syncthreads();
    }

    // rnorm reduce (overlay f32 [16][64] on lds_t; safe after final sync)
    float* red = (float*)&lds_t[0][0];
    #pragma unroll
    for (int j = 0; j < 4; ++j) red[cl * 64 + m4 * 4 + j] = ss[j];
    __syncthreads();
    if (t < 64) {
        float s = 0.f;
        #pragma unroll
        for (int i = 0; i < 16; ++i) s += red[i * 64 + t];
        rn_s[t] = 1.0f / fmaxf(sqrtf(s), EPSF);
    }
    __syncthreads();

    const float rnm = rn_s[wv * 16 + lr];

    // lane holds k = kt*16 + g*4 + r for its m = m0 + wv*16 + lr; softmax over k
    float l[16];
    #pragma unroll
    for (int kt = 0; kt < 4; ++kt) {
        float4 bb = *(const float4*)(bias + kt * 16 + g * 4);
        l[kt * 4 + 0] = acc[kt][0] * rnm + bb.x;
        l[kt * 4 + 1] = acc[kt][1] * rnm + bb.y;
        l[kt * 4 + 2] = acc[kt][2] * rnm + bb.z;
        l[kt * 4 + 3] = acc[kt][3] * rnm + bb.w;
    }
    float mx = l[0];
    #pragma unroll
    for (int i = 1; i < 16; ++i) mx = fmaxf(mx, l[i]);
    mx = fmaxf(mx, __shfl_xor(mx, 16));
    mx = fmaxf(mx, __shfl_xor(mx, 32));
    float s = 0.f;
    #pragma unroll
    for (int i = 0; i < 16; ++i) { l[i] = __expf(l[i] - mx); s += l[i]; }
    s += __shfl_xor(s, 16);
    s += __shfl_xor(s, 32);
    const float inv = 1.0f / s;
    #pragma unroll
    for (int kt = 0; kt < 4; ++kt)
        #pragma unroll
        for (int r = 0; r < 4; ++r)
            als[kt * 16 + g * 4 + r][wv * 16 + lr] = l[kt * 4 + r] * inv;
    __syncthreads();

    // write a' = a*rnorm (bf16) row-wise + asum partial (plain store)
    {
        const int k = t >> 2, q = t & 3;
        float spart = 0.f;
        unsigned short ub[16];
        #pragma unroll
        for (int i = 0; i < 16; ++i) {
            float a = als[k][q * 16 + i];
            spart += a;
            ub[i] = f2bf(a * rn_s[q * 16 + i]);
        }
        unsigned short* dst = ap + ((size_t)(n * KK + k)) * MM + m0 + q * 16;
        *(uint4*)dst = *(uint4*)&ub[0];
        *(uint4*)(dst + 8) = *(uint4*)&ub[8];
        spart += __shfl_xor(spart, 1);
        spart += __shfl_xor(spart, 2);
        if (q == 0) asum_part[((size_t)(n * 25 + mt)) * 64 + k] = spart;
    }
}

// ---------------------------------------------------------------------------
// agg: D[k=64][c16 per wave] = sum_m a'[k][m] * xb[c][m]. Each block owns
// (n, 64-c tile) for ALL m -> plain stores, no init. grid (8, 64), block 256.
// ---------------------------------------------------------------------------
__global__ __launch_bounds__(256) void aggm_kernel(
    const unsigned short* __restrict__ xb, const unsigned short* __restrict__ ap,
    float* __restrict__ agg)
{
    __shared__ __attribute__((aligned(16))) unsigned short als2[64][72];
    const int t    = threadIdx.x;
    const int n    = blockIdx.y;
    const int ct   = blockIdx.x;
    const int wv   = t >> 6;
    const int lane = t & 63;
    const int g    = lane >> 4;
    const int lr   = lane & 15;
    const int c_w  = ct * 64 + wv * 16;

    f32x4 acc[4];
    #pragma unroll
    for (int kt = 0; kt < 4; ++kt) acc[kt] = (f32x4){0.f, 0.f, 0.f, 0.f};

    const int ks = t >> 2, qs = t & 3;   // staging coords

    for (int mc = 0; mc < MM; mc += 64) {
        __syncthreads();
        {
            const unsigned short* src = ap + ((size_t)(n * KK + ks)) * MM + mc + qs * 16;
            uint4 w0 = *(const uint4*)src;
            uint4 w1 = *(const uint4*)(src + 8);
            *(uint4*)&als2[ks][qs * 16] = w0;
            *(uint4*)&als2[ks][qs * 16 + 8] = w1;
        }
        __syncthreads();
        #pragma unroll
        for (int msi = 0; msi < 2; ++msi) {
            const int ms = msi * 32;
            bf16x8 bf = *(const bf16x8*)(xb +
                ((size_t)(n * CC + c_w + lr)) * MM + mc + ms + g * 8);   // B^T row (c)
            #pragma unroll
            for (int kt = 0; kt < 4; ++kt) {
                bf16x8 af = *(const bf16x8*)&als2[kt * 16 + lr][ms + g * 8]; // A row (k)
                acc[kt] = __builtin_amdgcn_mfma_f32_16x16x32_bf16(af, bf, acc[kt], 0, 0, 0);
            }
        }
    }
    #pragma unroll
    for (int kt = 0; kt < 4; ++kt)
        #pragma unroll
        for (int r = 0; r < 4; ++r) {
            const int k = kt * 16 + g * 4 + r;
            agg[((size_t)(n * KK + k)) * CC + c_w + lr] = acc[kt][r];
        }
}

// ---------------------------------------------------------------------------
// vlad = agg - asum*cent, intra-normalize over C; write gns partial per (n,k)
// ---------------------------------------------------------------------------
__global__ __launch_bounds__(256) void vlad_kernel(
    const float* __restrict__ agg, const float* __restrict__ asum_part,
    const float* __restrict__ cent, float* __restrict__ out,
    float* __restrict__ gns_part)
{
    __shared__ float wsum[4];
    __shared__ float sinv;
    const int nk = blockIdx.x;          // n*64 + k
    const int n = nk >> 6, k = nk & 63;
    const int t = threadIdx.x;
    const int u = t & 63;

    // reduce asum over 25 m-tile partials (each wave redundantly)
    float pa = (u < 25) ? asum_part[((size_t)(n * 25 + u)) * 64 + k] : 0.f;
    #pragma unroll
    for (int o = 32; o > 0; o >>= 1) pa += __shfl_xor(pa, o);
    const float s = pa;

    float2 av = *(const float2*)(agg + (long)nk * CC + 2 * t);
    float2 cv = *(const float2*)(cent + (long)k * CC + 2 * t);
    float v0 = av.x - s * cv.x;
    float v1 = av.y - s * cv.y;
    float ss = v0 * v0 + v1 * v1;
    #pragma unroll
    for (int o = 32; o > 0; o >>= 1) ss += __shfl_down(ss, o);
    int wid = t >> 6;
    if (u == 0) wsum[wid] = ss;
    __syncthreads();
    if (t == 0) {
        float tot = wsum[0] + wsum[1] + wsum[2] + wsum[3];
        float inv = 1.0f / fmaxf(sqrtf(tot), EPSF);
        sinv = inv;
        gns_part[nk] = tot * inv * inv;
    }
    __syncthreads();
    float inv = sinv;
    float2 o2; o2.x = v0 * inv; o2.y = v1 * inv;
    *(float2*)(out + (long)nk * CC + 2 * t) = o2;
}

// ---------------------------------------------------------------------------
// global L2 scale per n (reduce 64 gns partials per wave, redundantly)
// ---------------------------------------------------------------------------
__global__ __launch_bounds__(256) void gscale_kernel(
    float* __restrict__ out, const float* __restrict__ gns_part)
{
    const int idx = blockIdx.x * 256 + threadIdx.x;   // float4 index
    const int n = blockIdx.x >> 5;                    // 32 blocks per n
    const int u = threadIdx.x & 63;
    float g = gns_part[n * 64 + u];
    #pragma unroll
    for (int o = 32; o > 0; o >>= 1) g += __shfl_xor(g, o);
    float inv = 1.0f / fmaxf(sqrtf(g), EPSF);
    float4 v = *(float4*)(out + (size_t)idx * 4);
    v.x *= inv; v.y *= inv; v.z *= inv; v.w *= inv;
    *(float4*)(out + (size_t)idx * 4) = v;
}

extern "C" void kernel_launch(void* const* d_in, const int* in_sizes, int n_in,
                              void* d_out, int out_size, void* d_ws, size_t ws_size,
                              hipStream_t stream)
{
    const float* x    = (const float*)d_in[0];
    const float* w    = (const float*)d_in[1];
    const float* bias = (const float*)d_in[2];
    const float* cent = (const float*)d_in[3];
    float* out = (float*)d_out;

    char* ws = (char*)d_ws;
    size_t off = 0;
    unsigned short* xb  = (unsigned short*)(ws + off); off += (size_t)NN * CC * MM * 2;
    unsigned short* ap  = (unsigned short*)(ws + off); off += (size_t)NN * KK * MM * 2;
    unsigned short* wb  = (unsigned short*)(ws + off); off += (size_t)KK * CC * 2;
    float* agg       = (float*)(ws + off); off += (size_t)NN * KK * CC * 4;
    float* asum_part = (float*)(ws + off); off += (size_t)NN * 25 * KK * 4;
    float* gns_part  = (float*)(ws + off); off += (size_t)NN * KK * 4;

    wconv_kernel <<<16, 256, 0, stream>>>(w, wb);
    fused1_kernel<<<dim3(25, 64), 256, 0, stream>>>(x, wb, bias, xb, ap, asum_part);
    aggm_kernel  <<<dim3(8, 64), 256, 0, stream>>>(xb, ap, agg);
    vlad_kernel  <<<NN * KK, 256, 0, stream>>>(agg, asum_part, cent, out, gns_part);
    gscale_kernel<<<(out_size / 4 + 255) / 256, 256, 0, stream>>>(out, gns_part);
}

// Round 4
// 126.458 us; speedup vs baseline: 5.1257x; 1.1007x over previous
//
#include <hip/hip_runtime.h>
#include <hip/hip_bf16.h>

#define NN 64
#define CC 512
#define MM 1600
#define KK 64
#define EPSF 1e-12f

typedef __attribute__((ext_vector_type(4))) float f32x4;
typedef __attribute__((ext_vector_type(8))) short bf16x8;

__device__ inline unsigned short f2bf(float f) {
    unsigned int u = __float_as_uint(f);
    unsigned int r = u + 0x7fffu + ((u >> 16) & 1u);   // RNE
    return (unsigned short)(r >> 16);
}

// ---------------------------------------------------------------------------
// w -> bf16
// ---------------------------------------------------------------------------
__global__ __launch_bounds__(256) void wconv_kernel(
    const float* __restrict__ w, unsigned short* __restrict__ wb)
{
    const int i = (blockIdx.x * 256 + threadIdx.x) * 8;
    float4 a = *(const float4*)(w + i);
    float4 b = *(const float4*)(w + i + 4);
    ushort4 u0, u1;
    u0.x = f2bf(a.x); u0.y = f2bf(a.y); u0.z = f2bf(a.z); u0.w = f2bf(a.w);
    u1.x = f2bf(b.x); u1.y = f2bf(b.y); u1.z = f2bf(b.z); u1.w = f2bf(b.w);
    *(ushort4*)(wb + i) = u0;
    *(ushort4*)(wb + i + 4) = u1;
}

// ---------------------------------------------------------------------------
// fused1: per (n, 64-m tile): x read straight from global (strided scalar f32,
// coalesced 64B segments), per-lane cvt->bf16 B-fragment, MFMA logits,
// per-lane sumsq -> rnorm via shfl, softmax over K, ap = a*rnorm bf16,
// asum partials. No LDS transpose (zero x-related bank conflicts).
// grid (25, 64), block 256.
// ---------------------------------------------------------------------------
__global__ __launch_bounds__(256) void fused1_kernel(
    const float* __restrict__ x, const unsigned short* __restrict__ wb,
    const float* __restrict__ bias,
    unsigned short* __restrict__ ap, float* __restrict__ asum_part)
{
    __shared__ float als[64][68];   // a (unscaled), [k][m]
    __shared__ float rn_s[64];

    const int t  = threadIdx.x;
    const int n  = blockIdx.y;
    const int mt = blockIdx.x;
    const int m0 = mt * 64;
    const int wv   = t >> 6;
    const int lane = t & 63;
    const int g    = lane >> 4;   // 0..3
    const int lr   = lane & 15;
    const int m_lane = m0 + wv * 16 + lr;

    f32x4 acc[4];
    #pragma unroll
    for (int kt = 0; kt < 4; ++kt) acc[kt] = (f32x4){0.f, 0.f, 0.f, 0.f};

    float ss = 0.f;
    const float* xcol = x + (size_t)n * CC * MM + m_lane;
    const unsigned short* wrow = wb + g * 8;

    #pragma unroll 2
    for (int cs = 0; cs < 16; ++cs) {
        const int cbase = cs * 32 + g * 8;
        float xv[8];
        #pragma unroll
        for (int j = 0; j < 8; ++j) xv[j] = xcol[(size_t)(cbase + j) * MM];
        bf16x8 bfrag;
        #pragma unroll
        for (int j = 0; j < 8; ++j) {
            ss += xv[j] * xv[j];
            bfrag[j] = (short)f2bf(xv[j]);
        }
        #pragma unroll
        for (int kt = 0; kt < 4; ++kt) {
            bf16x8 afrag = *(const bf16x8*)(wrow + (kt * 16 + lr) * CC + cs * 32);
            acc[kt] = __builtin_amdgcn_mfma_f32_16x16x32_bf16(afrag, bfrag, acc[kt], 0, 0, 0);
        }
    }

    // full sumsq for m_lane: reduce over the 4 g-slices
    ss += __shfl_xor(ss, 16);
    ss += __shfl_xor(ss, 32);
    const float rnm = 1.0f / fmaxf(sqrtf(ss), EPSF);
    if (g == 0) rn_s[wv * 16 + lr] = rnm;

    // lane holds k = kt*16 + g*4 + r for its m_lane; softmax over k
    float l[16];
    #pragma unroll
    for (int kt = 0; kt < 4; ++kt) {
        float4 bb = *(const float4*)(bias + kt * 16 + g * 4);
        l[kt * 4 + 0] = acc[kt][0] * rnm + bb.x;
        l[kt * 4 + 1] = acc[kt][1] * rnm + bb.y;
        l[kt * 4 + 2] = acc[kt][2] * rnm + bb.z;
        l[kt * 4 + 3] = acc[kt][3] * rnm + bb.w;
    }
    float mx = l[0];
    #pragma unroll
    for (int i = 1; i < 16; ++i) mx = fmaxf(mx, l[i]);
    mx = fmaxf(mx, __shfl_xor(mx, 16));
    mx = fmaxf(mx, __shfl_xor(mx, 32));
    float s = 0.f;
    #pragma unroll
    for (int i = 0; i < 16; ++i) { l[i] = __expf(l[i] - mx); s += l[i]; }
    s += __shfl_xor(s, 16);
    s += __shfl_xor(s, 32);
    const float inv = 1.0f / s;
    #pragma unroll
    for (int kt = 0; kt < 4; ++kt)
        #pragma unroll
        for (int r = 0; r < 4; ++r)
            als[kt * 16 + g * 4 + r][wv * 16 + lr] = l[kt * 4 + r] * inv;
    __syncthreads();

    // write a' = a*rnorm (bf16) row-wise + asum partial (plain store)
    {
        const int k = t >> 2, q = t & 3;
        float spart = 0.f;
        unsigned short ub[16];
        #pragma unroll
        for (int i = 0; i < 16; ++i) {
            float a = als[k][q * 16 + i];
            spart += a;
            ub[i] = f2bf(a * rn_s[q * 16 + i]);
        }
        unsigned short* dst = ap + ((size_t)(n * KK + k)) * MM + m0 + q * 16;
        *(uint4*)dst = *(uint4*)&ub[0];
        *(uint4*)(dst + 8) = *(uint4*)&ub[8];
        spart += __shfl_xor(spart, 1);
        spart += __shfl_xor(spart, 2);
        if (q == 0) asum_part[((size_t)(n * 25 + mt)) * 64 + k] = spart;
    }
}

// ---------------------------------------------------------------------------
// agg: D[k=64][c16 per wave] = sum_m a'[k][m] * x_bf16[c][m]; x read as f32
// from global (L3-resident after fused1), converted in-register. Each block
// owns (n, 64-c tile) for ALL m -> plain stores. grid (8, 64), block 256.
// ---------------------------------------------------------------------------
__global__ __launch_bounds__(256) void aggm_kernel(
    const float* __restrict__ x, const unsigned short* __restrict__ ap,
    float* __restrict__ agg)
{
    __shared__ __attribute__((aligned(16))) unsigned short als2[64][72];
    const int t    = threadIdx.x;
    const int n    = blockIdx.y;
    const int ct   = blockIdx.x;
    const int wv   = t >> 6;
    const int lane = t & 63;
    const int g    = lane >> 4;
    const int lr   = lane & 15;
    const int c_w  = ct * 64 + wv * 16;

    f32x4 acc[4];
    #pragma unroll
    for (int kt = 0; kt < 4; ++kt) acc[kt] = (f32x4){0.f, 0.f, 0.f, 0.f};

    const int ks = t >> 2, qs = t & 3;   // staging coords
    const float* xrow = x + ((size_t)(n * CC + c_w + lr)) * MM;

    for (int mc = 0; mc < MM; mc += 64) {
        __syncthreads();
        {
            const unsigned short* src = ap + ((size_t)(n * KK + ks)) * MM + mc + qs * 16;
            uint4 w0 = *(const uint4*)src;
            uint4 w1 = *(const uint4*)(src + 8);
            *(uint4*)&als2[ks][qs * 16] = w0;
            *(uint4*)&als2[ks][qs * 16 + 8] = w1;
        }
        __syncthreads();
        #pragma unroll
        for (int msi = 0; msi < 2; ++msi) {
            const int ms = msi * 32;
            float4 v0 = *(const float4*)(xrow + mc + ms + g * 8);
            float4 v1 = *(const float4*)(xrow + mc + ms + g * 8 + 4);
            bf16x8 bf;
            bf[0] = (short)f2bf(v0.x); bf[1] = (short)f2bf(v0.y);
            bf[2] = (short)f2bf(v0.z); bf[3] = (short)f2bf(v0.w);
            bf[4] = (short)f2bf(v1.x); bf[5] = (short)f2bf(v1.y);
            bf[6] = (short)f2bf(v1.z); bf[7] = (short)f2bf(v1.w);
            #pragma unroll
            for (int kt = 0; kt < 4; ++kt) {
                bf16x8 af = *(const bf16x8*)&als2[kt * 16 + lr][ms + g * 8]; // A row (k)
                acc[kt] = __builtin_amdgcn_mfma_f32_16x16x32_bf16(af, bf, acc[kt], 0, 0, 0);
            }
        }
    }
    #pragma unroll
    for (int kt = 0; kt < 4; ++kt)
        #pragma unroll
        for (int r = 0; r < 4; ++r) {
            const int k = kt * 16 + g * 4 + r;
            agg[((size_t)(n * KK + k)) * CC + c_w + lr] = acc[kt][r];
        }
}

// ---------------------------------------------------------------------------
// vlad = agg - asum*cent, intra-normalize over C; write gns partial per (n,k)
// ---------------------------------------------------------------------------
__global__ __launch_bounds__(256) void vlad_kernel(
    const float* __restrict__ agg, const float* __restrict__ asum_part,
    const float* __restrict__ cent, float* __restrict__ out,
    float* __restrict__ gns_part)
{
    __shared__ float wsum[4];
    __shared__ float sinv;
    const int nk = blockIdx.x;          // n*64 + k
    const int n = nk >> 6, k = nk & 63;
    const int t = threadIdx.x;
    const int u = t & 63;

    // reduce asum over 25 m-tile partials (each wave redundantly)
    float pa = (u < 25) ? asum_part[((size_t)(n * 25 + u)) * 64 + k] : 0.f;
    #pragma unroll
    for (int o = 32; o > 0; o >>= 1) pa += __shfl_xor(pa, o);
    const float s = pa;

    float2 av = *(const float2*)(agg + (long)nk * CC + 2 * t);
    float2 cv = *(const float2*)(cent + (long)k * CC + 2 * t);
    float v0 = av.x - s * cv.x;
    float v1 = av.y - s * cv.y;
    float ss = v0 * v0 + v1 * v1;
    #pragma unroll
    for (int o = 32; o > 0; o >>= 1) ss += __shfl_down(ss, o);
    int wid = t >> 6;
    if (u == 0) wsum[wid] = ss;
    __syncthreads();
    if (t == 0) {
        float tot = wsum[0] + wsum[1] + wsum[2] + wsum[3];
        float inv = 1.0f / fmaxf(sqrtf(tot), EPSF);
        sinv = inv;
        gns_part[nk] = tot * inv * inv;
    }
    __syncthreads();
    float inv = sinv;
    float2 o2; o2.x = v0 * inv; o2.y = v1 * inv;
    *(float2*)(out + (long)nk * CC + 2 * t) = o2;
}

// ---------------------------------------------------------------------------
// global L2 scale per n (reduce 64 gns partials per wave, redundantly)
// ---------------------------------------------------------------------------
__global__ __launch_bounds__(256) void gscale_kernel(
    float* __restrict__ out, const float* __restrict__ gns_part)
{
    const int idx = blockIdx.x * 256 + threadIdx.x;   // float4 index
    const int n = blockIdx.x >> 5;                    // 32 blocks per n
    const int u = threadIdx.x & 63;
    float g = gns_part[n * 64 + u];
    #pragma unroll
    for (int o = 32; o > 0; o >>= 1) g += __shfl_xor(g, o);
    float inv = 1.0f / fmaxf(sqrtf(g), EPSF);
    float4 v = *(float4*)(out + (size_t)idx * 4);
    v.x *= inv; v.y *= inv; v.z *= inv; v.w *= inv;
    *(float4*)(out + (size_t)idx * 4) = v;
}

extern "C" void kernel_launch(void* const* d_in, const int* in_sizes, int n_in,
                              void* d_out, int out_size, void* d_ws, size_t ws_size,
                              hipStream_t stream)
{
    const float* x    = (const float*)d_in[0];
    const float* w    = (const float*)d_in[1];
    const float* bias = (const float*)d_in[2];
    const float* cent = (const float*)d_in[3];
    float* out = (float*)d_out;

    char* ws = (char*)d_ws;
    size_t off = 0;
    unsigned short* ap  = (unsigned short*)(ws + off); off += (size_t)NN * KK * MM * 2;
    unsigned short* wb  = (unsigned short*)(ws + off); off += (size_t)KK * CC * 2;
    float* agg       = (float*)(ws + off); off += (size_t)NN * KK * CC * 4;
    float* asum_part = (float*)(ws + off); off += (size_t)NN * 25 * KK * 4;
    float* gns_part  = (float*)(ws + off); off += (size_t)NN * KK * 4;

    wconv_kernel <<<16, 256, 0, stream>>>(w, wb);
    fused1_kernel<<<dim3(25, 64), 256, 0, stream>>>(x, wb, bias, ap, asum_part);
    aggm_kernel  <<<dim3(8, 64), 256, 0, stream>>>(x, ap, agg);
    vlad_kernel  <<<NN * KK, 256, 0, stream>>>(agg, asum_part, cent, out, gns_part);
    gscale_kernel<<<(out_size / 4 + 255) / 256, 256, 0, stream>>>(out, gns_part);
}